// Round 5
// baseline (1596.459 us; speedup 1.0000x reference)
//
#include <hip/hip_runtime.h>

// 16-qubit statevector, 512 samples, 6 StronglyEntanglingLayers, qubit q <-> bit q.
// Round 12 = Round 11 with the nontemporal builtin type fixed (clang rejects
// HIP_vector_type float4; use native ext_vector_type(4)).
// Evidence (r10 rocprof): every sweepP, even pure-write P<0>, fetches exactly
// HALF its 128MB write volume -> 256B-sector write-allocate RMW; reads fully
// hit L3 (fetch == write-allocate only). nt stores kill the allocate-fetch;
// reads keep allocating so the chunk stays L3-resident. P also had 57% VALU
// (2x Q) -> move R_l(4,5,6) into Q(l-1) (legal: qubits 4-6 are lane bits in
// both tilings; ordering verified -- layer-(l-1) mid controls 5,6 precede the
// moved rots; wraps touch 4-6 only at l=5, so R_5(4) stays in P(5) after the
// deferred wraps, and only R_5(5),R_5(6) move into Q(4)).
//
// Schedule (r = l+1):
//   P'(l): locals a{0..3}, lanes a{4..9}(tid0-5); waves a{10..12}, fixed a{13..15}.
//          Deferred wraps of layer l-1, R_l(0..3), [l==5: R_5(4)], R_l(7,8,9),
//          ring prefix g=0..9-r (targets r..9).
//   Q'(l): locals a{0,10,11,12}, lanes a{4,5,6}+{13,14,15}; waves a{7,8,9},
//          fixed a{1,2,3}. R_l(10..15) (l>0), ring mid g=10-r..15-r (targets
//          10..15), then moved R_{l+1}(4,5,6) (l<=3) / R_5(5),R_5(6) (l==4).
//   P'(0): init = product of v_q = Rot_0(q)*RX(x_q)|0>, ring g=0..8.
//   finalK: layer-5 wraps (controls 10..15, targets 0..5) + measurement.
// Phys permutation: p0=a0 | p1-3=a4-6 | p4-6=a1-3 | p7-9=a10-12 | p10-12=a13-15
//   | p13-15=a7-9. Chunk = 256 samples (128 MB) for L3 residency.

#define NTH 512
typedef float v16f __attribute__((ext_vector_type(16)));
typedef float f4 __attribute__((ext_vector_type(4)));

template <int I> struct IC { static constexpr int value = I; };
template <int N, int I = 0, typename F>
__device__ __forceinline__ void static_for(F&& f) {
  if constexpr (I < N) { f(IC<I>{}); static_for<N, I + 1>(f); }
}

__device__ __forceinline__ void nt_store4(float2* p, float a, float b, float c, float d) {
  f4 v; v.x = a; v.y = b; v.z = c; v.w = d;
  __builtin_nontemporal_store(v, reinterpret_cast<f4*>(p));
}
__device__ __forceinline__ f4 nt_load4(const float2* p) {
  return __builtin_nontemporal_load(reinterpret_cast<const f4*>(p));
}

// element e -> amp-space local bits. SH=1: e = amp0-3 (P'). SH=10: amp0 + amp10-12 (Q').
template <int SH, int E> struct EIdx { static constexpr int v = (E & 1) | ((E >> 1) << SH); };

// ---------------- gate helpers on 16 reg amps ----------------

template <int LB>  // Rot on local e-bit LB
__device__ __forceinline__ void rot_local(v16f& ar, v16f& ai, const float* __restrict__ u) {
  const float u00r = u[0], u00i = u[1], u01r = u[2], u01i = u[3];
  const float u10r = u[4], u10i = u[5], u11r = u[6], u11i = u[7];
  static_for<8>([&](auto hc) {
    constexpr int h = hc.value;
    constexpr int e0 = ((h >> LB) << (LB + 1)) | (h & ((1 << LB) - 1));
    constexpr int e1 = e0 | (1 << LB);
    const float axr = ar[e0], axi = ai[e0], bxr = ar[e1], bxi = ai[e1];
    ar[e0] = u00r * axr - u00i * axi + u01r * bxr - u01i * bxi;
    ai[e0] = u00r * axi + u00i * axr + u01r * bxi + u01i * bxr;
    ar[e1] = u10r * axr - u10i * axi + u11r * bxr - u11i * bxi;
    ai[e1] = u10r * axi + u10i * axr + u11r * bxi + u11i * bxr;
  });
}

// Rot on a lane bit: shfl mask m, bit = this lane's bit value
__device__ __forceinline__ void rot_lane(v16f& ar, v16f& ai, const float* __restrict__ u,
                                         const int m, const int bit) {
  const float car = bit ? u[6] : u[0], cai = bit ? u[7] : u[1];
  const float cbr = bit ? u[4] : u[2], cbi = bit ? u[5] : u[3];
  static_for<16>([&](auto ec) {
    constexpr int e = ec.value;
    const float orr = ar[e], oii = ai[e];
    const float pr = __shfl_xor(orr, m);
    const float pi = __shfl_xor(oii, m);
    ar[e] = car * orr - cai * oii + cbr * pr - cbi * pi;
    ai[e] = car * oii + cai * orr + cbr * pi + cbi * pr;
  });
}

// CNOT, lane-bit target (shfl mask m), control amp-bit C (compile-time).
// C local -> static per-element participation; else branch on (ibase>>C)&1
// (shfl-safe: partner lane differs only in the target bit, so same take).
template <int SH, int C>
__device__ __forceinline__ void cnot_lane(v16f& ar, v16f& ai, const int m, const int ibase) {
  if constexpr ((EIdx<SH, 15>::v >> C) & 1) {
    static_for<16>([&](auto ec) {
      constexpr int e = ec.value;
      if constexpr ((EIdx<SH, e>::v >> C) & 1) {
        ar[e] = __shfl_xor(ar[e], m);
        ai[e] = __shfl_xor(ai[e], m);
      }
    });
  } else {
    if ((ibase >> C) & 1) {
      static_for<16>([&](auto ec) {
        constexpr int e = ec.value;
        ar[e] = __shfl_xor(ar[e], m);
        ai[e] = __shfl_xor(ai[e], m);
      });
    }
  }
}

// CNOT, local e-bit target TB, control amp-bit C (compile-time, C != target bit).
template <int TB, int SH, int C>
__device__ __forceinline__ void cnot_local(v16f& ar, v16f& ai, const int ibase) {
  static_for<8>([&](auto hc) {
    constexpr int h = hc.value;
    constexpr int e0 = ((h >> TB) << (TB + 1)) | (h & ((1 << TB) - 1));
    constexpr int e1 = e0 | (1 << TB);
    if constexpr ((EIdx<SH, 15>::v >> C) & 1) {
      if constexpr ((EIdx<SH, e0>::v >> C) & 1) {  // static: pure register swap
        const float tr = ar[e0], ti = ai[e0];
        ar[e0] = ar[e1]; ai[e0] = ai[e1];
        ar[e1] = tr;     ai[e1] = ti;
      }
    } else {
      const int take = (ibase >> C) & 1;
      const float axr = ar[e0], axi = ai[e0], bxr = ar[e1], bxi = ai[e1];
      ar[e0] = take ? bxr : axr; ai[e0] = take ? bxi : axi;
      ar[e1] = take ? axr : bxr; ai[e1] = take ? axi : bxi;
    }
  });
}

// ---------------- prep: 96 Rot matrices ----------------
__global__ void qsim_prep(const float* __restrict__ w, float* __restrict__ gm) {
  const int i = threadIdx.x;
  if (i < 96) {
    const float phi = w[i * 3 + 0];
    const float th  = w[i * 3 + 1];
    const float om  = w[i * 3 + 2];
    float st, ct; sincosf(0.5f * th, &st, &ct);
    float sa, ca; sincosf(0.5f * (phi + om), &sa, &ca);
    float sb, cb; sincosf(0.5f * (phi - om), &sb, &cb);
    float* u = gm + i * 8;
    u[0] =  ct * ca; u[1] = -ct * sa;   // m00
    u[2] = -st * cb; u[3] = -st * sb;   // m01
    u[4] =  st * cb; u[5] = -st * sb;   // m10
    u[6] =  ct * ca; u[7] =  ct * sa;   // m11
  }
}

// ---------------- Sweep P' : accessible {0..9} ----------------
template <int L>
__global__ void __launch_bounds__(NTH) sweepP(float2* __restrict__ st,
                                              const float* __restrict__ x,
                                              const float* __restrict__ gm) {
  const int tid = threadIdx.x;
  const int s  = blockIdx.x >> 3;
  const int fb = blockIdx.x & 7;
  // amp: e=a0-3 | a4-6=tid0-2 | a7-9=tid3-5 | a10-12=tid6-8 | a13-15=fb
  const int ibase = ((tid & 7) << 4) | (((tid >> 3) & 7) << 7) |
                    (((tid >> 6) & 7) << 10) | (fb << 13);
  // phys: a4-6->p1-3, a1-3->p4-6(eh), a10-12->p7-9, a13-15->p10-12, a7-9->p13-15
  const int pbase = ((tid & 7) << 1) | (((tid >> 6) & 7) << 7) | (fb << 10) |
                    (((tid >> 3) & 7) << 13);
  float2* __restrict__ base = st + (s << 16) + pbase;
  constexpr int r = L + 1;
  const float* __restrict__ gl = gm + L * 128;
  v16f ar, ai;

  if constexpr (L == 0) {
    // init: |psi> = prod_q v_q, v_q = Rot_0(q)*RX(x_q)|0>  (ALL 16 rots folded)
    __shared__ float iv[16][4];
    if (tid < 16) {
      const float* u = gm + tid * 8;
      float sx, cx; sincosf(0.5f * x[s * 16 + tid], &sx, &cx);
      iv[tid][0] = u[0] * cx + u[3] * sx;   // v0r
      iv[tid][1] = u[1] * cx - u[2] * sx;   // v0i
      iv[tid][2] = u[4] * cx + u[7] * sx;   // v1r
      iv[tid][3] = u[5] * cx - u[6] * sx;   // v1i
    }
    __syncthreads();
    float Tr = 1.f, Ti = 0.f;
    #pragma unroll
    for (int b = 4; b <= 15; ++b) {
      const int bit = (ibase >> b) & 1;
      const float fr = iv[b][2 * bit], fi = iv[b][2 * bit + 1];
      const float nr = Tr * fr - Ti * fi; Ti = Tr * fi + Ti * fr; Tr = nr;
    }
    ar[0] = Tr; ai[0] = Ti;
    // expand local e-bits 0..3 = qubits 0..3
    static_for<4>([&](auto bc) {
      constexpr int bI = bc.value;
      const float v0r = iv[bI][0], v0i = iv[bI][1], v1r = iv[bI][2], v1i = iv[bI][3];
      static_for<(1 << bI)>([&](auto kc) {
        constexpr int k = kc.value;
        constexpr int k1 = k | (1 << bI);
        const float kr = ar[k], ki = ai[k];
        ar[k1] = kr * v1r - ki * v1i; ai[k1] = kr * v1i + ki * v1r;
        ar[k]  = kr * v0r - ki * v0i; ai[k]  = kr * v0i + ki * v0r;
      });
    });
  } else {
    #pragma unroll
    for (int eh = 0; eh < 8; ++eh) {
      const float4 v = *reinterpret_cast<const float4*>(base + (eh << 4));
      ar[2 * eh] = v.x; ai[2 * eh] = v.y; ar[2 * eh + 1] = v.z; ai[2 * eh + 1] = v.w;
    }
    // deferred wrapped CNOT_{L-1}: control 16-L+k, target k (k=0..L-1)
    static_for<L>([&](auto kc) {
      constexpr int k = kc.value;
      constexpr int C = 16 - L + k;
      if constexpr (k <= 3) cnot_local<k, 1, C>(ar, ai, ibase);
      else                  cnot_lane<1, C>(ar, ai, 1 << (k - 4), ibase);
    });
    // R_L(0..3) local; R_L(4,5,6) moved to Q(L-1) (except R_5(4) which must
    // follow the layer-4 wrap targeting qubit 4 -> stays here, after wraps);
    // R_L(7,8,9) lane (tid3-5).
    rot_local<0>(ar, ai, gl);
    rot_local<1>(ar, ai, gl + 8);
    rot_local<2>(ar, ai, gl + 16);
    rot_local<3>(ar, ai, gl + 24);
    if constexpr (L == 5) rot_lane(ar, ai, gl + 32, 1, tid & 1);  // R_5(4)
    rot_lane(ar, ai, gl + 56, 8,  (tid >> 3) & 1);   // R_L(7)
    rot_lane(ar, ai, gl + 64, 16, (tid >> 4) & 1);   // R_L(8)
    rot_lane(ar, ai, gl + 72, 32, (tid >> 5) & 1);   // R_L(9)
  }

  // ring prefix g = 0..9-r, target t = g+r in [r, 9]
  static_for<10 - r>([&](auto gc) {
    constexpr int g = gc.value;
    constexpr int t = g + r;
    if constexpr (t <= 3) cnot_local<t, 1, g>(ar, ai, ibase);
    else                  cnot_lane<1, g>(ar, ai, 1 << (t - 4), ibase);
  });

  #pragma unroll
  for (int eh = 0; eh < 8; ++eh)
    nt_store4(base + (eh << 4), ar[2 * eh], ai[2 * eh], ar[2 * eh + 1], ai[2 * eh + 1]);
}

// ---------------- Sweep Q' : accessible {0,4,5,6,10..15} ----------------
template <int L>
__global__ void __launch_bounds__(NTH) sweepQ(float2* __restrict__ st,
                                              const float* __restrict__ gm) {
  const int tid = threadIdx.x;
  const int s  = blockIdx.x >> 3;
  const int fb = blockIdx.x & 7;
  // amp: e0=a0, e1-3=a10-12 | a4-6=tid0-2 | a13-15=tid3-5 | a7-9=tid6-8 | a1-3=fb
  const int ibase = ((tid & 7) << 4) | (((tid >> 3) & 7) << 13) |
                    (((tid >> 6) & 7) << 7) | (fb << 1);
  // phys: a4-6->p1-3, a1-3->p4-6, a10-12->p7-9(eh), a13-15->p10-12, a7-9->p13-15
  const int pbase = ((tid & 7) << 1) | (((tid >> 3) & 7) << 10) |
                    (((tid >> 6) & 7) << 13) | (fb << 4);
  float2* __restrict__ base = st + (s << 16) + pbase;
  constexpr int r = L + 1;
  const float* __restrict__ gl = gm + L * 128;
  v16f ar, ai;
  #pragma unroll
  for (int eh = 0; eh < 8; ++eh) {
    const float4 v = *reinterpret_cast<const float4*>(base + (eh << 7));
    ar[2 * eh] = v.x; ai[2 * eh] = v.y; ar[2 * eh + 1] = v.z; ai[2 * eh + 1] = v.w;
  }
  if constexpr (L > 0) {  // layer 0's rots were folded into init
    rot_local<1>(ar, ai, gl + 80);                    // R(10)
    rot_local<2>(ar, ai, gl + 88);                    // R(11)
    rot_local<3>(ar, ai, gl + 96);                    // R(12)
    rot_lane(ar, ai, gl + 104, 8,  (tid >> 3) & 1);   // R(13)
    rot_lane(ar, ai, gl + 112, 16, (tid >> 4) & 1);   // R(14)
    rot_lane(ar, ai, gl + 120, 32, (tid >> 5) & 1);   // R(15)
  }
  // ring mid g = 10-r .. 15-r, target t = g+r in [10,15]
  static_for<6>([&](auto gc) {
    constexpr int g = 10 - r + gc.value;
    constexpr int t = g + r;
    if constexpr (t >= 13) cnot_lane<10, g>(ar, ai, 1 << (t - 10), ibase);
    else                   cnot_local<t - 9, 10, g>(ar, ai, ibase);
  });
  // moved-in head rots of layer L+1 on lane qubits 4,5,6 (after mid-chain
  // controls 5,6 of this layer; wraps of layer L never touch 4-6 for L<=4).
  if constexpr (L <= 3) {
    const float* __restrict__ gn = gm + (L + 1) * 128;
    rot_lane(ar, ai, gn + 32, 1, tid & 1);            // R_{L+1}(4)
    rot_lane(ar, ai, gn + 40, 2, (tid >> 1) & 1);     // R_{L+1}(5)
    rot_lane(ar, ai, gn + 48, 4, (tid >> 2) & 1);     // R_{L+1}(6)
  }
  if constexpr (L == 4) {
    const float* __restrict__ gn = gm + 5 * 128;
    rot_lane(ar, ai, gn + 40, 2, (tid >> 1) & 1);     // R_5(5)
    rot_lane(ar, ai, gn + 48, 4, (tid >> 2) & 1);     // R_5(6)
  }

  #pragma unroll
  for (int eh = 0; eh < 8; ++eh)
    nt_store4(base + (eh << 7), ar[2 * eh], ai[2 * eh], ar[2 * eh + 1], ai[2 * eh + 1]);
}

// ---------------- final: 6 wrapped CNOT_5 + measurement (read-only) ----------------
__global__ void __launch_bounds__(NTH) finalK(const float2* __restrict__ st,
                                              float* __restrict__ part) {
  const int tid = threadIdx.x;
  const int s  = blockIdx.x >> 3;
  const int fb = blockIdx.x & 7;
  const int ibase = ((tid & 7) << 4) | (((tid >> 3) & 7) << 7) |
                    (((tid >> 6) & 7) << 10) | (fb << 13);
  const int pbase = ((tid & 7) << 1) | (((tid >> 6) & 7) << 7) | (fb << 10) |
                    (((tid >> 3) & 7) << 13);
  const float2* __restrict__ base = st + (s << 16) + pbase;
  v16f ar, ai;
  #pragma unroll
  for (int eh = 0; eh < 8; ++eh) {
    const f4 v = nt_load4(base + (eh << 4));
    ar[2 * eh] = v.x; ai[2 * eh] = v.y; ar[2 * eh + 1] = v.z; ai[2 * eh + 1] = v.w;
  }
  // deferred CNOT_5 (r=6): control 10+k, target k (k=0..5); controls are
  // wave bits (10-12) or fb bits (13-15) -> thread-uniform.
  static_for<6>([&](auto kc) {
    constexpr int k = kc.value;
    constexpr int C = 10 + k;
    if constexpr (k <= 3) cnot_local<k, 1, C>(ar, ai, ibase);
    else                  cnot_lane<1, C>(ar, ai, 1 << (k - 4), ibase);
  });
  // measurement: <Z_q> partials per block
  __shared__ float red[8][16];
  float tot = 0.f, sl0 = 0.f, sl1 = 0.f, sl2 = 0.f, sl3 = 0.f;
  static_for<16>([&](auto ec) {
    constexpr int e = ec.value;
    const float p = ar[e] * ar[e] + ai[e] * ai[e];
    tot += p;
    if constexpr (e & 1) sl0 -= p; else sl0 += p;
    if constexpr (e & 2) sl1 -= p; else sl1 += p;
    if constexpr (e & 4) sl2 -= p; else sl2 += p;
    if constexpr (e & 8) sl3 -= p; else sl3 += p;
  });
  const float sl[4] = {sl0, sl1, sl2, sl3};
  const int wv = tid >> 6;
  static_for<16>([&](auto qc) {
    constexpr int q = qc.value;
    float v;
    if constexpr (q < 4) v = sl[q];
    else v = ((ibase >> q) & 1) ? -tot : tot;
    v += __shfl_xor(v, 1);  v += __shfl_xor(v, 2);  v += __shfl_xor(v, 4);
    v += __shfl_xor(v, 8);  v += __shfl_xor(v, 16); v += __shfl_xor(v, 32);
    if ((tid & 63) == 0) red[wv][q] = v;
  });
  __syncthreads();
  if (tid < 16) {
    float a = 0.f;
    #pragma unroll
    for (int w8 = 0; w8 < 8; ++w8) a += red[w8][tid];
    part[blockIdx.x * 16 + tid] = a;
  }
}

// ---------------- final reduce: 8 block-partials -> out ----------------
__global__ void __launch_bounds__(NTH) reduceK(const float* __restrict__ part,
                                               float* __restrict__ out) {
  const int j = blockIdx.x * NTH + threadIdx.x;  // j = s*16 + q, j < 8192
  const int s = j >> 4, q = j & 15;
  float a = 0.f;
  #pragma unroll
  for (int fb = 0; fb < 8; ++fb) a += part[(s << 7) + fb * 16 + q];
  out[j] = a;
}

extern "C" void kernel_launch(void* const* d_in, const int* in_sizes, int n_in,
                              void* d_out, int out_size, void* d_ws, size_t ws_size,
                              hipStream_t stream) {
  (void)in_sizes; (void)n_in; (void)out_size;
  const float* x = (const float*)d_in[0];
  const float* w = (const float*)d_in[1];
  float* out = (float*)d_out;
  float* gm   = (float*)d_ws;                          // 768 floats
  float* part = (float*)((char*)d_ws + 4096);          // 512*8*16 floats = 256 KB
  float2* st  = (float2*)((char*)d_ws + 524288);       // state, chunked to fit ws

  const size_t avail = ws_size > 524288 ? ws_size - 524288 : 0;
  long long chunk = (long long)(avail / 524288);       // 512 KB per sample
  if (chunk > 256) chunk = 256;                        // 128 MB: L3-resident chunk
  if (chunk < 1) chunk = 1;

  qsim_prep<<<dim3(1), dim3(128), 0, stream>>>(w, gm);
  for (int s0 = 0; s0 < 512; s0 += (int)chunk) {
    const int ns = (512 - s0) < (int)chunk ? (512 - s0) : (int)chunk;
    const dim3 g(ns * 8), b(NTH);
    const float* xs = x + s0 * 16;
    float* pp = part + (size_t)s0 * 128;
    sweepP<0><<<g, b, 0, stream>>>(st, xs, gm);
    sweepQ<0><<<g, b, 0, stream>>>(st, gm);
    sweepP<1><<<g, b, 0, stream>>>(st, xs, gm);
    sweepQ<1><<<g, b, 0, stream>>>(st, gm);
    sweepP<2><<<g, b, 0, stream>>>(st, xs, gm);
    sweepQ<2><<<g, b, 0, stream>>>(st, gm);
    sweepP<3><<<g, b, 0, stream>>>(st, xs, gm);
    sweepQ<3><<<g, b, 0, stream>>>(st, gm);
    sweepP<4><<<g, b, 0, stream>>>(st, xs, gm);
    sweepQ<4><<<g, b, 0, stream>>>(st, gm);
    sweepP<5><<<g, b, 0, stream>>>(st, xs, gm);
    sweepQ<5><<<g, b, 0, stream>>>(st, gm);
    finalK<<<g, b, 0, stream>>>(st, pp);
  }
  reduceK<<<dim3(16), dim3(NTH), 0, stream>>>(part, out);
}

// Round 6
// 1424.981 us; speedup vs baseline: 1.1203x; 1.1203x over previous
//
#include <hip/hip_runtime.h>

// 16-qubit statevector, 512 samples, 6 StronglyEntanglingLayers, qubit q <-> bit q.
// Round 13: composed CNOT lane-permutation passes + even rot_lane split.
// Evidence: across r3/r5 the slow sweep is ALWAYS the one with 6 rot_lanes
// (store policy swap r3->r5 swapped which kernel was slow ONLY because the
// rots moved too). DS bpermute work above ~170/sweep stops hiding under the
// 128MB R+W memory floor (~40us) at our low occupancy. Fixes:
//  (a) all ring CNOTs with lane-bit targets in a pass compose into ONE
//      permutation gather (32 bperm) -- locals are never targets, so the
//      source REGISTER index stays thread-local; source LANE = XOR cascade
//      unwound newest-first (controls: lane bits from the unwound index,
//      local bits from constexpr e, wave/fixed from ibase).
//  (b) flexible rots R_l(4,5,6): R(4)->P(l), R(5),R(6)->Q(l-1). P: 4 lane-rots,
//      Q: 5. (R(7,8,9) stuck in P, R(13,14,15) stuck in Q by accessibility.)
// Schedule (r = l+1):
//   P'(l): locals a{0..3}, lanes a{4..9}(tid0-5); waves a{10..12}, fixed a{13..15}.
//          wraps_{l-1} -> R_l(0..3) local -> R_l(4) -> R_l(7,8,9) ->
//          prefix: cnot_local (t<=3) then composed pass (t in [4,9]).
//   Q'(l): locals a{0,10,11,12}, lanes a{4,5,6}(tid0-2)+{13,14,15}(tid3-5);
//          waves a{7,8,9}, fixed a{1,2,3}. R_l(10..12) local, R_l(13..15) lane,
//          mid: cnot_local (t=10..12) then composed pass (t=13..15), then
//          moved R_{l+1}(5),R_{l+1}(6) (l<=4).
//   P'(0): init = product of v_q = Rot_0(q)*RX(x_q)|0>, then prefix.
//   finalK: layer-5 wraps + measurement. Phys permutation unchanged:
//   p0=a0 | p1-3=a4-6 | p4-6=a1-3 | p7-9=a10-12 | p10-12=a13-15 | p13-15=a7-9.
// Chunk = 256 samples (128 MB). nt stores kept (neutral).

#define NTH 512
typedef float v16f __attribute__((ext_vector_type(16)));
typedef float f4 __attribute__((ext_vector_type(4)));

template <int I> struct IC { static constexpr int value = I; };
template <int N, int I = 0, typename F>
__device__ __forceinline__ void static_for(F&& f) {
  if constexpr (I < N) { f(IC<I>{}); static_for<N, I + 1>(f); }
}

__device__ __forceinline__ void nt_store4(float2* p, float a, float b, float c, float d) {
  f4 v; v.x = a; v.y = b; v.z = c; v.w = d;
  __builtin_nontemporal_store(v, reinterpret_cast<f4*>(p));
}
__device__ __forceinline__ f4 nt_load4(const float2* p) {
  return __builtin_nontemporal_load(reinterpret_cast<const f4*>(p));
}

// element e -> amp-space local bits. SH=1: e = amp0-3 (P'). SH=10: amp0 + amp10-12 (Q').
template <int SH, int E> struct EIdx { static constexpr int v = (E & 1) | ((E >> 1) << SH); };

// ---------------- gate helpers on 16 reg amps ----------------

template <int LB>  // Rot on local e-bit LB
__device__ __forceinline__ void rot_local(v16f& ar, v16f& ai, const float* __restrict__ u) {
  const float u00r = u[0], u00i = u[1], u01r = u[2], u01i = u[3];
  const float u10r = u[4], u10i = u[5], u11r = u[6], u11i = u[7];
  static_for<8>([&](auto hc) {
    constexpr int h = hc.value;
    constexpr int e0 = ((h >> LB) << (LB + 1)) | (h & ((1 << LB) - 1));
    constexpr int e1 = e0 | (1 << LB);
    const float axr = ar[e0], axi = ai[e0], bxr = ar[e1], bxi = ai[e1];
    ar[e0] = u00r * axr - u00i * axi + u01r * bxr - u01i * bxi;
    ai[e0] = u00r * axi + u00i * axr + u01r * bxi + u01i * bxr;
    ar[e1] = u10r * axr - u10i * axi + u11r * bxr - u11i * bxi;
    ai[e1] = u10r * axi + u10i * axr + u11r * bxi + u11i * bxr;
  });
}

// Rot on a lane bit: shfl mask m, bit = this lane's bit value
__device__ __forceinline__ void rot_lane(v16f& ar, v16f& ai, const float* __restrict__ u,
                                         const int m, const int bit) {
  const float car = bit ? u[6] : u[0], cai = bit ? u[7] : u[1];
  const float cbr = bit ? u[4] : u[2], cbi = bit ? u[5] : u[3];
  static_for<16>([&](auto ec) {
    constexpr int e = ec.value;
    const float orr = ar[e], oii = ai[e];
    const float pr = __shfl_xor(orr, m);
    const float pi = __shfl_xor(oii, m);
    ar[e] = car * orr - cai * oii + cbr * pr - cbi * pi;
    ai[e] = car * oii + cai * orr + cbr * pi + cbi * pr;
  });
}

// CNOT, lane-bit target (shfl mask m), control amp-bit C (compile-time).
template <int SH, int C>
__device__ __forceinline__ void cnot_lane(v16f& ar, v16f& ai, const int m, const int ibase) {
  if constexpr ((EIdx<SH, 15>::v >> C) & 1) {
    static_for<16>([&](auto ec) {
      constexpr int e = ec.value;
      if constexpr ((EIdx<SH, e>::v >> C) & 1) {
        ar[e] = __shfl_xor(ar[e], m);
        ai[e] = __shfl_xor(ai[e], m);
      }
    });
  } else {
    if ((ibase >> C) & 1) {
      static_for<16>([&](auto ec) {
        constexpr int e = ec.value;
        ar[e] = __shfl_xor(ar[e], m);
        ai[e] = __shfl_xor(ai[e], m);
      });
    }
  }
}

// CNOT, local e-bit target TB, control amp-bit C (compile-time, C != target bit).
template <int TB, int SH, int C>
__device__ __forceinline__ void cnot_local(v16f& ar, v16f& ai, const int ibase) {
  static_for<8>([&](auto hc) {
    constexpr int h = hc.value;
    constexpr int e0 = ((h >> TB) << (TB + 1)) | (h & ((1 << TB) - 1));
    constexpr int e1 = e0 | (1 << TB);
    if constexpr ((EIdx<SH, 15>::v >> C) & 1) {
      if constexpr ((EIdx<SH, e0>::v >> C) & 1) {  // static: pure register swap
        const float tr = ar[e0], ti = ai[e0];
        ar[e0] = ar[e1]; ai[e0] = ai[e1];
        ar[e1] = tr;     ai[e1] = ti;
      }
    } else {
      const int take = (ibase >> C) & 1;
      const float axr = ar[e0], axi = ai[e0], bxr = ar[e1], bxi = ai[e1];
      ar[e0] = take ? bxr : axr; ai[e0] = take ? bxi : axi;
      ar[e1] = take ? axr : bxr; ai[e1] = take ? axi : bxi;
    }
  });
}

// ---------------- prep: 96 Rot matrices ----------------
__global__ void qsim_prep(const float* __restrict__ w, float* __restrict__ gm) {
  const int i = threadIdx.x;
  if (i < 96) {
    const float phi = w[i * 3 + 0];
    const float th  = w[i * 3 + 1];
    const float om  = w[i * 3 + 2];
    float st, ct; sincosf(0.5f * th, &st, &ct);
    float sa, ca; sincosf(0.5f * (phi + om), &sa, &ca);
    float sb, cb; sincosf(0.5f * (phi - om), &sb, &cb);
    float* u = gm + i * 8;
    u[0] =  ct * ca; u[1] = -ct * sa;   // m00
    u[2] = -st * cb; u[3] = -st * sb;   // m01
    u[4] =  st * cb; u[5] = -st * sb;   // m10
    u[6] =  ct * ca; u[7] =  ct * sa;   // m11
  }
}

// ---------------- Sweep P' : accessible {0..9} ----------------
template <int L>
__global__ void __launch_bounds__(NTH) sweepP(float2* __restrict__ st,
                                              const float* __restrict__ x,
                                              const float* __restrict__ gm) {
  const int tid = threadIdx.x;
  const int s  = blockIdx.x >> 3;
  const int fb = blockIdx.x & 7;
  // amp: e=a0-3 | a4-6=tid0-2 | a7-9=tid3-5 | a10-12=tid6-8 | a13-15=fb
  const int ibase = ((tid & 7) << 4) | (((tid >> 3) & 7) << 7) |
                    (((tid >> 6) & 7) << 10) | (fb << 13);
  // phys: a4-6->p1-3, a1-3->p4-6(eh), a10-12->p7-9, a13-15->p10-12, a7-9->p13-15
  const int pbase = ((tid & 7) << 1) | (((tid >> 6) & 7) << 7) | (fb << 10) |
                    (((tid >> 3) & 7) << 13);
  float2* __restrict__ base = st + (s << 16) + pbase;
  constexpr int r = L + 1;
  const float* __restrict__ gl = gm + L * 128;
  v16f ar, ai;

  if constexpr (L == 0) {
    // init: |psi> = prod_q v_q, v_q = Rot_0(q)*RX(x_q)|0>  (ALL 16 rots folded)
    __shared__ float iv[16][4];
    if (tid < 16) {
      const float* u = gm + tid * 8;
      float sx, cx; sincosf(0.5f * x[s * 16 + tid], &sx, &cx);
      iv[tid][0] = u[0] * cx + u[3] * sx;   // v0r
      iv[tid][1] = u[1] * cx - u[2] * sx;   // v0i
      iv[tid][2] = u[4] * cx + u[7] * sx;   // v1r
      iv[tid][3] = u[5] * cx - u[6] * sx;   // v1i
    }
    __syncthreads();
    float Tr = 1.f, Ti = 0.f;
    #pragma unroll
    for (int b = 4; b <= 15; ++b) {
      const int bit = (ibase >> b) & 1;
      const float fr = iv[b][2 * bit], fi = iv[b][2 * bit + 1];
      const float nr = Tr * fr - Ti * fi; Ti = Tr * fi + Ti * fr; Tr = nr;
    }
    ar[0] = Tr; ai[0] = Ti;
    // expand local e-bits 0..3 = qubits 0..3
    static_for<4>([&](auto bc) {
      constexpr int bI = bc.value;
      const float v0r = iv[bI][0], v0i = iv[bI][1], v1r = iv[bI][2], v1i = iv[bI][3];
      static_for<(1 << bI)>([&](auto kc) {
        constexpr int k = kc.value;
        constexpr int k1 = k | (1 << bI);
        const float kr = ar[k], ki = ai[k];
        ar[k1] = kr * v1r - ki * v1i; ai[k1] = kr * v1i + ki * v1r;
        ar[k]  = kr * v0r - ki * v0i; ai[k]  = kr * v0i + ki * v0r;
      });
    });
  } else {
    #pragma unroll
    for (int eh = 0; eh < 8; ++eh) {
      const float4 v = *reinterpret_cast<const float4*>(base + (eh << 4));
      ar[2 * eh] = v.x; ai[2 * eh] = v.y; ar[2 * eh + 1] = v.z; ai[2 * eh + 1] = v.w;
    }
    // deferred wrapped CNOT_{L-1}: control 16-L+k, target k (k=0..L-1)
    static_for<L>([&](auto kc) {
      constexpr int k = kc.value;
      constexpr int C = 16 - L + k;
      if constexpr (k <= 3) cnot_local<k, 1, C>(ar, ai, ibase);
      else                  cnot_lane<1, C>(ar, ai, 1 << (k - 4), ibase);
    });
    // R_L(0..3) local; R_L(4) lane; R_L(5),R_L(6) ran in Q(L-1); R_L(7,8,9) lane
    rot_local<0>(ar, ai, gl);
    rot_local<1>(ar, ai, gl + 8);
    rot_local<2>(ar, ai, gl + 16);
    rot_local<3>(ar, ai, gl + 24);
    rot_lane(ar, ai, gl + 32, 1, tid & 1);           // R_L(4)
    rot_lane(ar, ai, gl + 56, 8,  (tid >> 3) & 1);   // R_L(7)
    rot_lane(ar, ai, gl + 64, 16, (tid >> 4) & 1);   // R_L(8)
    rot_lane(ar, ai, gl + 72, 32, (tid >> 5) & 1);   // R_L(9)
  }

  // ring prefix, local targets first: g = 0..3-r (t = g+r <= 3)
  if constexpr (r <= 3) {
    static_for<4 - r>([&](auto gc) {
      constexpr int g = gc.value;
      cnot_local<g + r, 1, g>(ar, ai, ibase);
    });
  }
  // composed lane-target pass: g = max(0,4-r)..9-r, t = g+r in [4,9] (lane tid0-5).
  // src lane = XOR cascade unwound newest-first; local controls from constexpr e.
  {
    constexpr int G0 = (r <= 3) ? (4 - r) : 0;
    constexpr int G1 = 9 - r;
    static_for<16>([&](auto ec) {
      constexpr int e = ec.value;
      int v = tid & 63;
      static_for<G1 - G0 + 1>([&](auto jc) {
        constexpr int g = G1 - jc.value;       // newest gate first
        constexpr int t = g + r;
        int cb;
        if constexpr (g <= 3) cb = (e >> g) & 1;        // local control
        else                  cb = (v >> (g - 4)) & 1;  // lane control (current v)
        v ^= cb << (t - 4);
      });
      ar[e] = __shfl(ar[e], v);
      ai[e] = __shfl(ai[e], v);
    });
  }

  #pragma unroll
  for (int eh = 0; eh < 8; ++eh)
    nt_store4(base + (eh << 4), ar[2 * eh], ai[2 * eh], ar[2 * eh + 1], ai[2 * eh + 1]);
}

// ---------------- Sweep Q' : accessible {0,4,5,6,10..15} ----------------
template <int L>
__global__ void __launch_bounds__(NTH) sweepQ(float2* __restrict__ st,
                                              const float* __restrict__ gm) {
  const int tid = threadIdx.x;
  const int s  = blockIdx.x >> 3;
  const int fb = blockIdx.x & 7;
  // amp: e0=a0, e1-3=a10-12 | a4-6=tid0-2 | a13-15=tid3-5 | a7-9=tid6-8 | a1-3=fb
  const int ibase = ((tid & 7) << 4) | (((tid >> 3) & 7) << 13) |
                    (((tid >> 6) & 7) << 7) | (fb << 1);
  // phys: a4-6->p1-3, a1-3->p4-6, a10-12->p7-9(eh), a13-15->p10-12, a7-9->p13-15
  const int pbase = ((tid & 7) << 1) | (((tid >> 3) & 7) << 10) |
                    (((tid >> 6) & 7) << 13) | (fb << 4);
  float2* __restrict__ base = st + (s << 16) + pbase;
  constexpr int r = L + 1;
  const float* __restrict__ gl = gm + L * 128;
  v16f ar, ai;
  #pragma unroll
  for (int eh = 0; eh < 8; ++eh) {
    const float4 v = *reinterpret_cast<const float4*>(base + (eh << 7));
    ar[2 * eh] = v.x; ai[2 * eh] = v.y; ar[2 * eh + 1] = v.z; ai[2 * eh + 1] = v.w;
  }
  if constexpr (L > 0) {  // layer 0's rots were folded into init
    rot_local<1>(ar, ai, gl + 80);                    // R(10)
    rot_local<2>(ar, ai, gl + 88);                    // R(11)
    rot_local<3>(ar, ai, gl + 96);                    // R(12)
    rot_lane(ar, ai, gl + 104, 8,  (tid >> 3) & 1);   // R(13)
    rot_lane(ar, ai, gl + 112, 16, (tid >> 4) & 1);   // R(14)
    rot_lane(ar, ai, gl + 120, 32, (tid >> 5) & 1);   // R(15)
  }
  // ring mid, local targets first: g = 10-r..12-r (t = 10,11,12 -> e1-3)
  static_for<3>([&](auto gc) {
    constexpr int g = 10 - r + gc.value;
    cnot_local<g + r - 9, 10, g>(ar, ai, ibase);
  });
  // composed lane-target pass: g = 13-r..15-r, t = 13,14,15 (lane tid3-5).
  static_for<16>([&](auto ec) {
    constexpr int e = ec.value;
    int v = tid & 63;
    static_for<3>([&](auto jc) {
      constexpr int g = (15 - r) - jc.value;     // newest gate first
      constexpr int t = g + r;
      int cb;
      if constexpr (g >= 13)      cb = (v >> (g - 10)) & 1;  // lane control a13,a14
      else if constexpr (g >= 10) cb = (e >> (g - 9)) & 1;   // local control a10-12
      else                        cb = (ibase >> g) & 1;     // wave control a7-9
      v ^= cb << (t - 10);
    });
    ar[e] = __shfl(ar[e], v);
    ai[e] = __shfl(ai[e], v);
  });
  // moved-in head rots of layer L+1 on lane qubits 5,6 (R_{L+1}(4) stays in P).
  if constexpr (L <= 4) {
    const float* __restrict__ gn = gm + (L + 1) * 128;
    rot_lane(ar, ai, gn + 40, 2, (tid >> 1) & 1);     // R_{L+1}(5)
    rot_lane(ar, ai, gn + 48, 4, (tid >> 2) & 1);     // R_{L+1}(6)
  }

  #pragma unroll
  for (int eh = 0; eh < 8; ++eh)
    nt_store4(base + (eh << 7), ar[2 * eh], ai[2 * eh], ar[2 * eh + 1], ai[2 * eh + 1]);
}

// ---------------- final: 6 wrapped CNOT_5 + measurement (read-only) ----------------
__global__ void __launch_bounds__(NTH) finalK(const float2* __restrict__ st,
                                              float* __restrict__ part) {
  const int tid = threadIdx.x;
  const int s  = blockIdx.x >> 3;
  const int fb = blockIdx.x & 7;
  const int ibase = ((tid & 7) << 4) | (((tid >> 3) & 7) << 7) |
                    (((tid >> 6) & 7) << 10) | (fb << 13);
  const int pbase = ((tid & 7) << 1) | (((tid >> 6) & 7) << 7) | (fb << 10) |
                    (((tid >> 3) & 7) << 13);
  const float2* __restrict__ base = st + (s << 16) + pbase;
  v16f ar, ai;
  #pragma unroll
  for (int eh = 0; eh < 8; ++eh) {
    const f4 v = nt_load4(base + (eh << 4));
    ar[2 * eh] = v.x; ai[2 * eh] = v.y; ar[2 * eh + 1] = v.z; ai[2 * eh + 1] = v.w;
  }
  // deferred CNOT_5 (r=6): control 10+k, target k (k=0..5); controls are
  // wave bits (10-12) or fb bits (13-15) -> thread-uniform.
  static_for<6>([&](auto kc) {
    constexpr int k = kc.value;
    constexpr int C = 10 + k;
    if constexpr (k <= 3) cnot_local<k, 1, C>(ar, ai, ibase);
    else                  cnot_lane<1, C>(ar, ai, 1 << (k - 4), ibase);
  });
  // measurement: <Z_q> partials per block
  __shared__ float red[8][16];
  float tot = 0.f, sl0 = 0.f, sl1 = 0.f, sl2 = 0.f, sl3 = 0.f;
  static_for<16>([&](auto ec) {
    constexpr int e = ec.value;
    const float p = ar[e] * ar[e] + ai[e] * ai[e];
    tot += p;
    if constexpr (e & 1) sl0 -= p; else sl0 += p;
    if constexpr (e & 2) sl1 -= p; else sl1 += p;
    if constexpr (e & 4) sl2 -= p; else sl2 += p;
    if constexpr (e & 8) sl3 -= p; else sl3 += p;
  });
  const float sl[4] = {sl0, sl1, sl2, sl3};
  const int wv = tid >> 6;
  static_for<16>([&](auto qc) {
    constexpr int q = qc.value;
    float v;
    if constexpr (q < 4) v = sl[q];
    else v = ((ibase >> q) & 1) ? -tot : tot;
    v += __shfl_xor(v, 1);  v += __shfl_xor(v, 2);  v += __shfl_xor(v, 4);
    v += __shfl_xor(v, 8);  v += __shfl_xor(v, 16); v += __shfl_xor(v, 32);
    if ((tid & 63) == 0) red[wv][q] = v;
  });
  __syncthreads();
  if (tid < 16) {
    float a = 0.f;
    #pragma unroll
    for (int w8 = 0; w8 < 8; ++w8) a += red[w8][tid];
    part[blockIdx.x * 16 + tid] = a;
  }
}

// ---------------- final reduce: 8 block-partials -> out ----------------
__global__ void __launch_bounds__(NTH) reduceK(const float* __restrict__ part,
                                               float* __restrict__ out) {
  const int j = blockIdx.x * NTH + threadIdx.x;  // j = s*16 + q, j < 8192
  const int s = j >> 4, q = j & 15;
  float a = 0.f;
  #pragma unroll
  for (int fb = 0; fb < 8; ++fb) a += part[(s << 7) + fb * 16 + q];
  out[j] = a;
}

extern "C" void kernel_launch(void* const* d_in, const int* in_sizes, int n_in,
                              void* d_out, int out_size, void* d_ws, size_t ws_size,
                              hipStream_t stream) {
  (void)in_sizes; (void)n_in; (void)out_size;
  const float* x = (const float*)d_in[0];
  const float* w = (const float*)d_in[1];
  float* out = (float*)d_out;
  float* gm   = (float*)d_ws;                          // 768 floats
  float* part = (float*)((char*)d_ws + 4096);          // 512*8*16 floats = 256 KB
  float2* st  = (float2*)((char*)d_ws + 524288);       // state, chunked to fit ws

  const size_t avail = ws_size > 524288 ? ws_size - 524288 : 0;
  long long chunk = (long long)(avail / 524288);       // 512 KB per sample
  if (chunk > 256) chunk = 256;                        // 128 MB chunk
  if (chunk < 1) chunk = 1;

  qsim_prep<<<dim3(1), dim3(128), 0, stream>>>(w, gm);
  for (int s0 = 0; s0 < 512; s0 += (int)chunk) {
    const int ns = (512 - s0) < (int)chunk ? (512 - s0) : (int)chunk;
    const dim3 g(ns * 8), b(NTH);
    const float* xs = x + s0 * 16;
    float* pp = part + (size_t)s0 * 128;
    sweepP<0><<<g, b, 0, stream>>>(st, xs, gm);
    sweepQ<0><<<g, b, 0, stream>>>(st, gm);
    sweepP<1><<<g, b, 0, stream>>>(st, xs, gm);
    sweepQ<1><<<g, b, 0, stream>>>(st, gm);
    sweepP<2><<<g, b, 0, stream>>>(st, xs, gm);
    sweepQ<2><<<g, b, 0, stream>>>(st, gm);
    sweepP<3><<<g, b, 0, stream>>>(st, xs, gm);
    sweepQ<3><<<g, b, 0, stream>>>(st, gm);
    sweepP<4><<<g, b, 0, stream>>>(st, xs, gm);
    sweepQ<4><<<g, b, 0, stream>>>(st, gm);
    sweepP<5><<<g, b, 0, stream>>>(st, xs, gm);
    sweepQ<5><<<g, b, 0, stream>>>(st, gm);
    finalK<<<g, b, 0, stream>>>(st, pp);
  }
  reduceK<<<dim3(16), dim3(NTH), 0, stream>>>(part, out);
}